// Round 15
// baseline (2995.887 us; speedup 1.0000x reference)
//
#include <hip/hip_runtime.h>
#include <hip/hip_bf16.h>
#include <stdint.h>

#define TT 1024
#define DD 512
#define HH 512

typedef short bf16x8 __attribute__((ext_vector_type(8)));
typedef float f32x4 __attribute__((ext_vector_type(4)));
typedef unsigned long long u64;
typedef unsigned int u32;
typedef unsigned short u16;

// ---- workspace layout (bytes) ---- (identical to r5/r11/r14)
#define OFF_WPACK 0ull
#define SZ_WPACK  (32ull*4*4*8*1024)
#define OFF_XS    (OFF_WPACK + SZ_WPACK)
#define SZ_XS     (1024ull*4*2*8*1024)
#define OFF_HB    (OFF_XS + SZ_XS)
#define SZ_HB     (4ull*4*4096*8)

__device__ __forceinline__ u16 f2bf(float f){
  u32 u = __builtin_bit_cast(u32, f);
  u32 r = (u + 0x7fffu + ((u >> 16) & 1u)) >> 16;   // RNE
  return (u16)r;
}

// ---- clear all hbuf tags every launch (no cross-replay state) ----
__global__ void k_clear(u64* hb){
  int id = blockIdx.x * 256 + threadIdx.x;          // 65536
  hb[id] = 0x8000000000000000ull;
}

// ---- pack Wcat=[Wx;Wh] into B-frags (verified r5/r11/r14) ----
__global__ void k_pack_w(const float* __restrict__ Wx, const float* __restrict__ Wh,
                         u16* __restrict__ wp){
  int id = blockIdx.x * 256 + threadIdx.x;          // 262144
  int lane = id & 63;
  int kk = (id >> 6) & 7, G = (id >> 9) & 3, q = (id >> 11) & 3, p = id >> 13;
  int col = G * 512 + p * 16 + (lane & 15);
  int kb  = q * 256 + kk * 32 + (lane >> 4) * 8;
  union { u16 v[8]; uint4 u; } pk;
#pragma unroll
  for (int j = 0; j < 8; ++j){
    int k = kb + j;
    float f = (k < 512) ? Wx[k * 2048 + col] : Wh[(k - 512) * 2048 + col];
    pk.v[j] = f2bf(f);
  }
  long long fid = ((p * 4 + q) * 4 + G) * 8 + kk;
  *((uint4*)wp + fid * 64 + lane) = pk.u;
}

// ---- x -> per-(t,g,q,kk) M=16 A-frag blob (verified r5/r11/r14) ----
__global__ void k_conv_x(const float* __restrict__ x, uint4* __restrict__ xs){
  int id = blockIdx.x * 256 + threadIdx.x;          // 4,194,304
  int lane = id & 63, kk = (id >> 6) & 7, q = (id >> 9) & 1, g = (id >> 10) & 3, t = id >> 12;
  int row = g * 16 + (lane & 15);
  int k   = q * 256 + kk * 32 + (lane >> 4) * 8;
  const float* src = x + ((long long)row * TT + t) * DD + k;
  union { u16 v[8]; uint4 u; } pk;
#pragma unroll
  for (int j = 0; j < 8; ++j) pk.v[j] = f2bf(src[j]);
  xs[id] = pk.u;
}

// ---- h0 -> tagged words, buf 3, tag 0xFFFFFFFF (verified r5/r11/r14) ----
__global__ void k_conv_h0(const float* __restrict__ h0, u64* __restrict__ hb){
  int id = blockIdx.x * 256 + threadIdx.x;          // 16384
  int row = id & 15, cp = (id >> 4) & 255, g = id >> 12;
  u32 v0 = f2bf(h0[(g * 16 + row) * HH + 2 * cp]);
  u32 v1 = f2bf(h0[(g * 16 + row) * HH + 2 * cp + 1]);
  hb[((size_t)g * 4 + 3) * 4096 + cp * 16 + row] =
      (0xFFFFFFFFull << 32) | ((u64)v1 << 16) | v0;
}

// ---- persistent scan: 128 wgs (4 groups x 32) x 256 threads ----
// r15 = r14 + sentinel pre-poll: h-waves wait on a 1-load-per-lane sample
// (one word per publisher block, per-consumer-distinct offsets) -> 32x less
// MALL poll traffic while waiting; the full 32-load loop then serves as
// fetch+verify (expected single pass). Everything else r14-verbatim.
__launch_bounds__(256, 1)
__global__ void k_lstm(const float* __restrict__ bias_g, float* __restrict__ out,
                       const u16* __restrict__ wp, const uint4* __restrict__ xs,
                       u64* __restrict__ hbufs)
{
  __shared__ float xpart[2][2][1088];   // [buf][xq][G*272 + row*17 + col]
  __shared__ float hpart[2][2][1088];   // [buf][hw][G*272 + row*17 + col]
  __shared__ int sflag[12];             // 0..3 xf; 4..7 hp; 8..9 gd

  const int tid  = threadIdx.x;
  const int lane = tid & 63;
  const int q    = tid >> 6;
  const int w    = blockIdx.x;
  const int g    = w >> 5;
  const int p    = w & 31;
  const int khi  = lane >> 4;
  const int llo  = lane & 15;

  if (tid < 12) sflag[tid] = -1;
  __syncthreads();   // startup only

  // persistent B fragments: 32 frags = 128 VGPRs
  bf16x8 bfrag[4][8];
  {
    const bf16x8* wpf = (const bf16x8*)wp;
#pragma unroll
    for (int G = 0; G < 4; ++G)
#pragma unroll
      for (int kk = 0; kk < 8; ++kk)
        bfrag[G][kk] = wpf[(((p * 4 + q) * 4 + G) * 8 + kk) * 64 + lane];
  }

  u64* gb = hbufs + (size_t)g * 4 * 4096;

  if (q < 2){
    // ------------- x-wave: free-runs <=2 ahead, partials producer -------------
    for (int t = 0; t < TT; ++t){
      const int buf = t & 1;
      const uint4* xb = xs + ((((size_t)t * 4 + g) * 2 + q) * 8) * 64 + lane;
      uint4 xf8[8];
#pragma unroll
      for (int kk = 0; kk < 8; ++kk) xf8[kk] = xb[kk * 64];
      for (;;){
        int g0 = __hip_atomic_load(&sflag[8], __ATOMIC_RELAXED, __HIP_MEMORY_SCOPE_WORKGROUP);
        int g1 = __hip_atomic_load(&sflag[9], __ATOMIC_RELAXED, __HIP_MEMORY_SCOPE_WORKGROUP);
        if (g0 >= t - 2 && g1 >= t - 2) break;
      }
      f32x4 acc[4];
#pragma unroll
      for (int G = 0; G < 4; ++G) acc[G] = (f32x4){0.f, 0.f, 0.f, 0.f};
#pragma unroll
      for (int kk = 0; kk < 8; ++kk){
        bf16x8 av = __builtin_bit_cast(bf16x8, xf8[kk]);
#pragma unroll
        for (int G = 0; G < 4; ++G)
          acc[G] = __builtin_amdgcn_mfma_f32_16x16x32_bf16(av, bfrag[G][kk], acc[G], 0, 0, 0);
      }
      float* pp = &xpart[buf][q][0];
#pragma unroll
      for (int G = 0; G < 4; ++G)
#pragma unroll
        for (int reg = 0; reg < 4; ++reg)
          pp[G * 272 + (khi * 4 + reg) * 17 + llo] = acc[G][reg];
      asm volatile("s_waitcnt lgkmcnt(0)" ::: "memory");
      __hip_atomic_store(&sflag[buf * 2 + q], t, __ATOMIC_RELAXED, __HIP_MEMORY_SCOPE_WORKGROUP);
    }
  } else {
    // ------------- h-wave: sentinel -> fetch+verify -> MFMA -> gates -> publish -------------
    const int hw = q - 2;
    const int wbase = ((hw * 128 + khi * 4) * 16) + llo;    // consumer (r11/r14 verbatim)
    const int cp4 = khi;
    const int r   = llo;
    const int c0  = hw * 8 + 2 * cp4;
    float bia[2][4];
#pragma unroll
    for (int e = 0; e < 2; ++e)
#pragma unroll
      for (int G = 0; G < 4; ++G)
        bia[e][G] = bias_g[G * 512 + p * 16 + c0 + e];
    float cs[2] = {0.f, 0.f};
    const int swidx = (p * 8 + hw * 4 + cp4) * 16 + r;
    float* outp = out + ((size_t)(g * 16 + r) * TT) * HH + p * 16 + c0;
    float pend0 = 0.f, pend1 = 0.f;
    // sentinel: lane pair samples one word per publisher block of this half;
    // per-consumer-distinct in-block offset -> each buffer word sampled once chip-wide
    const int sentidx = (hw * 32 + (lane >> 1)) * 64 + p * 2 + (lane & 1);

    for (int t = 0; t < TT; ++t){
      const int buf = t & 1;
      const u64* bb = gb + (size_t)((t + 3) & 3) * 4096;
      const u32 tg = (u32)(t - 1);
      // ---- sentinel pre-poll: 1 load/lane, low-traffic wait ----
      {
        const u64* sp = bb + sentidx;
        u64 sv;
        do {
          sv = __hip_atomic_load(sp, __ATOMIC_RELAXED, __HIP_MEMORY_SCOPE_AGENT);
        } while (!__all((u32)(sv >> 32) == tg));
      }
      // ---- full fetch + verify (expected 1 pass) ----
      u64 wv[32];
      for (;;){
#pragma unroll
        for (int j = 0; j < 32; ++j){
          int kk = j >> 2, jj = j & 3;
          wv[j] = __hip_atomic_load(bb + wbase + kk * 256 + jj * 16,
                                    __ATOMIC_RELAXED, __HIP_MEMORY_SCOPE_AGENT);
        }
        bool ok = true;
#pragma unroll
        for (int j = 0; j < 32; ++j) ok &= ((u32)(wv[j] >> 32) == tg);
        if (__all(ok)) break;
      }
      asm volatile("" ::: "memory");
      // deferred out store of step t-1 (HBM ack overlaps this step's MFMA)
      if (t > 0) *(float2*)(outp + (size_t)(t - 1) * HH) = make_float2(pend0, pend1);

      f32x4 acc[4];
#pragma unroll
      for (int n = 0; n < 4; ++n) acc[n] = (f32x4){0.f, 0.f, 0.f, 0.f};
#pragma unroll
      for (int kk = 0; kk < 8; ++kk){
        union { u32 d[4]; bf16x8 v; } af;
#pragma unroll
        for (int jj = 0; jj < 4; ++jj) af.d[jj] = (u32)wv[kk * 4 + jj];
#pragma unroll
        for (int n = 0; n < 4; ++n)
          acc[n] = __builtin_amdgcn_mfma_f32_16x16x32_bf16(af.v, bfrag[n][kk], acc[n], 0, 0, 0);
      }
      for (;;){
        int go = __hip_atomic_load(&sflag[8 + (hw ^ 1)], __ATOMIC_RELAXED, __HIP_MEMORY_SCOPE_WORKGROUP);
        if (go >= t - 2) break;
      }
      float* hp_ = &hpart[buf][hw][0];
#pragma unroll
      for (int G = 0; G < 4; ++G)
#pragma unroll
        for (int reg = 0; reg < 4; ++reg)
          hp_[G * 272 + (khi * 4 + reg) * 17 + llo] = acc[G][reg];
      asm volatile("s_waitcnt lgkmcnt(0)" ::: "memory");
      __hip_atomic_store(&sflag[4 + buf * 2 + hw], t, __ATOMIC_RELAXED, __HIP_MEMORY_SCOPE_WORKGROUP);
      for (;;){
        int f0 = __hip_atomic_load(&sflag[buf * 2],     __ATOMIC_RELAXED, __HIP_MEMORY_SCOPE_WORKGROUP);
        int f1 = __hip_atomic_load(&sflag[buf * 2 + 1], __ATOMIC_RELAXED, __HIP_MEMORY_SCOPE_WORKGROUP);
        int f2 = __hip_atomic_load(&sflag[4 + buf * 2 + (hw ^ 1)], __ATOMIC_RELAXED, __HIP_MEMORY_SCOPE_WORKGROUP);
        if (f0 >= t && f1 >= t && f2 >= t) break;
      }
      asm volatile("s_waitcnt lgkmcnt(0)" ::: "memory");
      __builtin_amdgcn_sched_barrier(0);

      // gate pre-activations in r11's exact addition order: x0 + x1 + h0 + h1 + bias
      const float* x0 = &xpart[buf][0][0];
      const float* x1 = &xpart[buf][1][0];
      const float* h0p = &hpart[buf][0][0];
      const float* h1p = &hpart[buf][1][0];
      float aG[2][4];
#pragma unroll
      for (int e = 0; e < 2; ++e)
#pragma unroll
        for (int G = 0; G < 4; ++G){
          int idx = G * 272 + r * 17 + c0 + e;
          aG[e][G] = x0[idx] + x1[idx] + h0p[idx] + h1p[idx] + bia[e][G];
        }
      asm volatile("s_waitcnt lgkmcnt(0)" ::: "memory");
      __builtin_amdgcn_sched_barrier(0);
      __hip_atomic_store(&sflag[8 + hw], t, __ATOMIC_RELAXED, __HIP_MEMORY_SCOPE_WORKGROUP);

      float hv[2]; u32 h16[2];
#pragma unroll
      for (int e = 0; e < 2; ++e){
        float gi = 1.f / (1.f + __expf(-aG[e][0]));
        float gf = 1.f / (1.f + __expf(-aG[e][1]));
        float go = 1.f / (1.f + __expf(-aG[e][2]));
        float e2 = __expf(-2.f * fabsf(aG[e][3]));
        float gg = __builtin_copysignf((1.f - e2) / (1.f + e2), aG[e][3]);
        float c  = gf * cs[e] + gi * gg;
        cs[e] = c;
        float ec = __expf(-2.f * fabsf(c));
        float th = __builtin_copysignf((1.f - ec) / (1.f + ec), c);
        hv[e] = go * th;
        h16[e] = f2bf(hv[e]);
      }
      // publish straight from the pipeline (critical path)
      u64 word = ((u64)(u32)t << 32) | ((u64)h16[1] << 16) | (u64)h16[0];
      __hip_atomic_store(gb + (size_t)(t & 3) * 4096 + swidx, word,
                         __ATOMIC_RELAXED, __HIP_MEMORY_SCOPE_AGENT);
      pend0 = hv[0]; pend1 = hv[1];
    }
    *(float2*)(outp + (size_t)(TT - 1) * HH) = make_float2(pend0, pend1);
  }
}

extern "C" void kernel_launch(void* const* d_in, const int* in_sizes, int n_in,
                              void* d_out, int out_size, void* d_ws, size_t ws_size,
                              hipStream_t stream){
  const float* x  = (const float*)d_in[0];
  const float* h0 = (const float*)d_in[1];
  const float* Wx = (const float*)d_in[2];
  const float* Wh = (const float*)d_in[3];
  const float* b  = (const float*)d_in[4];
  float* out = (float*)d_out;

  unsigned char* ws = (unsigned char*)d_ws;
  u16*   wp = (u16*)(ws + OFF_WPACK);
  uint4* xs = (uint4*)(ws + OFF_XS);
  u64*   hb = (u64*)(ws + OFF_HB);

  hipLaunchKernelGGL(k_clear,   dim3(256),   dim3(256), 0, stream, hb);
  hipLaunchKernelGGL(k_pack_w,  dim3(1024),  dim3(256), 0, stream, Wx, Wh, wp);
  hipLaunchKernelGGL(k_conv_x,  dim3(16384), dim3(256), 0, stream, x, xs);
  hipLaunchKernelGGL(k_conv_h0, dim3(64),    dim3(256), 0, stream, h0, hb);
  hipLaunchKernelGGL(k_lstm,    dim3(128),   dim3(256), 0, stream, b, out, wp, xs, hb);
}

// Round 17
// 2937.170 us; speedup vs baseline: 1.0200x; 1.0200x over previous
//
#include <hip/hip_runtime.h>
#include <hip/hip_bf16.h>
#include <stdint.h>

#define TT 1024
#define DD 512
#define HH 512

typedef short bf16x8 __attribute__((ext_vector_type(8)));
typedef float f32x4 __attribute__((ext_vector_type(4)));
typedef unsigned long long u64;
typedef unsigned int u32;
typedef unsigned short u16;

// ---- workspace layout (bytes) ----
#define OFF_WPACK 0ull
#define SZ_WPACK  (32ull*4*4*8*1024)          // 4 MiB B-frags (p,q,G,kk) — r14 verbatim
#define OFF_XS    (OFF_WPACK + SZ_WPACK)       // 64 MiB x A-frag blobs, 8 groups x 8 rows
#define SZ_XS     (1024ull*8*2*8*512)
#define OFF_HBL   (OFF_XS + SZ_XS)             // local tagged h: [g8][buf4][2048 u64] = 512 KiB
#define SZ_HB1    (8ull*4*2048*8)
#define OFF_HBM   (OFF_HBL + SZ_HB1)           // mirror tagged h (MALL), same layout
#define OFF_ORG   (OFF_HBM + SZ_HB1)           // cnt[8] + total, u32

__device__ __forceinline__ u16 f2bf(float f){
  u32 u = __builtin_bit_cast(u32, f);
  u32 r = (u + 0x7fffu + ((u >> 16) & 1u)) >> 16;   // RNE
  return (u16)r;
}

// ---- clear tags + org every launch (agent stores; no cross-replay state) ----
__global__ void k_clear(u64* hbl, u64* hbm, u32* org){
  int id = blockIdx.x * 256 + threadIdx.x;          // 65536
  __hip_atomic_store(hbl + id, 0x8000000000000000ull, __ATOMIC_RELAXED, __HIP_MEMORY_SCOPE_AGENT);
  __hip_atomic_store(hbm + id, 0x8000000000000000ull, __ATOMIC_RELAXED, __HIP_MEMORY_SCOPE_AGENT);
  if (id < 16) __hip_atomic_store(org + id, 0u, __ATOMIC_RELAXED, __HIP_MEMORY_SCOPE_AGENT);
}

// ---- pack Wcat=[Wx;Wh] into B-frags (verified r5/r11/r14) ----
__global__ void k_pack_w(const float* __restrict__ Wx, const float* __restrict__ Wh,
                         u16* __restrict__ wp){
  int id = blockIdx.x * 256 + threadIdx.x;          // 262144
  int lane = id & 63;
  int kk = (id >> 6) & 7, G = (id >> 9) & 3, q = (id >> 11) & 3, p = id >> 13;
  int col = G * 512 + p * 16 + (lane & 15);
  int kb  = q * 256 + kk * 32 + (lane >> 4) * 8;
  union { u16 v[8]; uint4 u; } pk;
#pragma unroll
  for (int j = 0; j < 8; ++j){
    int k = kb + j;
    float f = (k < 512) ? Wx[k * 2048 + col] : Wh[(k - 512) * 2048 + col];
    pk.v[j] = f2bf(f);
  }
  long long fid = ((p * 4 + q) * 4 + G) * 8 + kk;
  *((uint4*)wp + fid * 64 + lane) = pk.u;
}

// ---- x -> per-(t,g<8,q<2,kk<8) 8-row half-frag blobs, 512 B each (r8-validated) ----
__global__ void k_conv_x(const float* __restrict__ x, unsigned char* __restrict__ xs){
  int id = blockIdx.x * 256 + threadIdx.x;          // 4,194,304
  int ksub = id & 3, row = (id >> 2) & 7, kk = (id >> 5) & 7;
  int q = (id >> 8) & 1, g = (id >> 9) & 7, t = id >> 12;
  int k = q * 256 + kk * 32 + ksub * 8;
  const float* src = x + ((long long)(g * 8 + row) * TT + t) * DD + k;
  union { u16 v[8]; uint4 u; } pk;
#pragma unroll
  for (int j = 0; j < 8; ++j) pk.v[j] = f2bf(src[j]);
  size_t dst = ((((size_t)t * 8 + g) * 2 + q) * 8 + kk) * 512 + (size_t)(ksub * 128 + row * 16);
  *(uint4*)(xs + dst) = pk.u;
}

// ---- h0 -> tagged words, buf 3, tag 0xFFFFFFFF, BOTH buffers (agent stores) ----
__global__ void k_conv_h0(const float* __restrict__ h0, u64* __restrict__ hbl,
                          u64* __restrict__ hbm){
  int id = blockIdx.x * 256 + threadIdx.x;          // 16384
  int row = id & 7, c = (id >> 3) & 255, g = id >> 11;
  u32 v0 = f2bf(h0[(g * 8 + row) * HH + 2 * c]);
  u32 v1 = f2bf(h0[(g * 8 + row) * HH + 2 * c + 1]);
  u64 wd = (0xFFFFFFFFull << 32) | ((u64)v1 << 16) | v0;
  size_t idx = ((size_t)g * 4 + 3) * 2048 + c * 8 + row;
  __hip_atomic_store(hbl + idx, wd, __ATOMIC_RELAXED, __HIP_MEMORY_SCOPE_AGENT);
  __hip_atomic_store(hbm + idx, wd, __ATOMIC_RELAXED, __HIP_MEMORY_SCOPE_AGENT);
}

#define LDL(I, B, OFF) asm volatile("global_load_dwordx2 %0, %1, off offset:" OFF " sc0" \
                                    : "=v"(wv[I]) : "v"(B))
#define LDL32(B0, B1) do { \
  LDL(0,B0,"0");    LDL(1,B0,"64");   LDL(2,B0,"128");  LDL(3,B0,"192");   \
  LDL(4,B0,"1024"); LDL(5,B0,"1088"); LDL(6,B0,"1152"); LDL(7,B0,"1216");  \
  LDL(8,B0,"2048"); LDL(9,B0,"2112"); LDL(10,B0,"2176");LDL(11,B0,"2240"); \
  LDL(12,B0,"3072");LDL(13,B0,"3136");LDL(14,B0,"3200");LDL(15,B0,"3264"); \
  LDL(16,B1,"0");    LDL(17,B1,"64");   LDL(18,B1,"128");  LDL(19,B1,"192");   \
  LDL(20,B1,"1024"); LDL(21,B1,"1088"); LDL(22,B1,"1152"); LDL(23,B1,"1216");  \
  LDL(24,B1,"2048"); LDL(25,B1,"2112"); LDL(26,B1,"2176"); LDL(27,B1,"2240");  \
  LDL(28,B1,"3072"); LDL(29,B1,"3136"); LDL(30,B1,"3200"); LDL(31,B1,"3264");  \
  asm volatile("s_waitcnt vmcnt(0)" ::: "memory"); } while(0)

// ---- persistent scan: 256 wgs (8 groups x 32) x 256 threads, 1 wg/CU ----
// Startup self-org: group = physical XCC_ID, column slot = arrival rank;
// validated (cnt[x]==32 forall x), else logical identity + mirror-only.
// Exchange: dual-publish (local plain store + mirror agent store); consume
// via bounded sc0 local poll -> mirror fallback; adaptive give-up.
// r17 = r16 + lane<32 guard on the deferred out-store (r16's race bug).
__launch_bounds__(256, 1)
__global__ void k_lstm(const float* __restrict__ bias_g, float* __restrict__ out,
                       const u16* __restrict__ wp, const unsigned char* __restrict__ xs,
                       u64* __restrict__ hbl, u64* __restrict__ hbm, u32* __restrict__ org)
{
  __shared__ float xpart[2][2][1088];   // [buf][xq][G*272 + row*17 + col]
  __shared__ float hpart[2][2][1088];   // [buf][hw][G*272 + row*17 + col]
  __shared__ int sflag[12];             // 0..3 xf; 4..7 hp; 8..9 gd
  __shared__ int sorg[4];               // g, p, valid
  __shared__ float lds_pad[14336];      // 56 KB: forces 1 wg/CU (160K LDS cap)

  const int tid  = threadIdx.x;
  const int lane = tid & 63;
  const int q    = tid >> 6;
  const int khi  = lane >> 4;
  const int llo  = lane & 15;

  if ((int)blockDim.x == 123456) lds_pad[tid] = bias_g[tid];  // keep pad alive

  if (tid < 12) sflag[tid] = -1;
  // ---- startup self-organization ----
  if (tid == 0){
    u32 xcc;
    asm volatile("s_getreg_b32 %0, hwreg(20, 0, 32)" : "=s"(xcc));  // HW_REG_XCC_ID
    xcc &= 0xffu;
    u32 myp = 0xffffu;
    if (xcc < 8)
      myp = __hip_atomic_fetch_add(org + xcc, 1u, __ATOMIC_RELAXED, __HIP_MEMORY_SCOPE_AGENT);
    __hip_atomic_fetch_add(org + 8, 1u, __ATOMIC_RELEASE, __HIP_MEMORY_SCOPE_AGENT);
    while (__hip_atomic_load(org + 8, __ATOMIC_ACQUIRE, __HIP_MEMORY_SCOPE_AGENT) < 256u) {}
    bool valid = (xcc < 8) && (myp < 32);
#pragma unroll
    for (int i = 0; i < 8; ++i)
      valid &= (__hip_atomic_load(org + i, __ATOMIC_RELAXED, __HIP_MEMORY_SCOPE_AGENT) == 32u);
    sorg[0] = valid ? (int)xcc : (int)(blockIdx.x & 7);
    sorg[1] = valid ? (int)myp : (int)(blockIdx.x >> 3);
    sorg[2] = valid ? 1 : 0;
  }
  __syncthreads();
  const int g = sorg[0];
  const int p = sorg[1];
  const bool valid = (sorg[2] != 0);

  // persistent B fragments: 32 frags = 128 VGPRs
  bf16x8 bfrag[4][8];
  {
    const bf16x8* wpf = (const bf16x8*)wp;
#pragma unroll
    for (int G = 0; G < 4; ++G)
#pragma unroll
      for (int kk = 0; kk < 8; ++kk)
        bfrag[G][kk] = wpf[(((p * 4 + q) * 4 + G) * 8 + kk) * 64 + lane];
  }

  u64* gbl = hbl + (size_t)g * 4 * 2048;
  u64* gbm = hbm + (size_t)g * 4 * 2048;

  if (q < 2){
    // ------------- x-wave: free-runs <=2 ahead, partials producer -------------
    const int xoff = khi * 128 + (lane & 7) * 16;
    for (int t = 0; t < TT; ++t){
      const int buf = t & 1;
      const unsigned char* xb = xs + ((((size_t)t * 8 + g) * 2 + q) * 8) * 512 + xoff;
      uint4 xf8[8];
#pragma unroll
      for (int kk = 0; kk < 8; ++kk) xf8[kk] = *(const uint4*)(xb + kk * 512);
      for (;;){
        int g0 = __hip_atomic_load(&sflag[8], __ATOMIC_RELAXED, __HIP_MEMORY_SCOPE_WORKGROUP);
        int g1 = __hip_atomic_load(&sflag[9], __ATOMIC_RELAXED, __HIP_MEMORY_SCOPE_WORKGROUP);
        if (g0 >= t - 2 && g1 >= t - 2) break;
      }
      f32x4 acc[4];
#pragma unroll
      for (int G = 0; G < 4; ++G) acc[G] = (f32x4){0.f, 0.f, 0.f, 0.f};
#pragma unroll
      for (int kk = 0; kk < 8; ++kk){
        bf16x8 av = __builtin_bit_cast(bf16x8, xf8[kk]);
#pragma unroll
        for (int G = 0; G < 4; ++G)
          acc[G] = __builtin_amdgcn_mfma_f32_16x16x32_bf16(av, bfrag[G][kk], acc[G], 0, 0, 0);
      }
      float* pp = &xpart[buf][q][0];
#pragma unroll
      for (int G = 0; G < 4; ++G)
#pragma unroll
        for (int reg = 0; reg < 4; ++reg)
          pp[G * 272 + (khi * 4 + reg) * 17 + llo] = acc[G][reg];
      asm volatile("s_waitcnt lgkmcnt(0)" ::: "memory");
      __hip_atomic_store(&sflag[buf * 2 + q], t, __ATOMIC_RELAXED, __HIP_MEMORY_SCOPE_WORKGROUP);
    }
  } else {
    // ------------- h-wave: poll(local->mirror) -> MFMA -> combine -> gates -> dual-publish -------------
    const int hw = q - 2;
    const int wbase = hw * 1024 + khi * 32 + (lane & 7);    // consumer word base
    const int r8_  = lane & 7;                              // gate row (lanes<32)
    const int cp4  = (lane >> 3) & 3;                       // gate col pair
    const int c0   = hw * 8 + 2 * cp4;
    float bia[2][4];
#pragma unroll
    for (int e = 0; e < 2; ++e)
#pragma unroll
      for (int G = 0; G < 4; ++G)
        bia[e][G] = bias_g[G * 512 + p * 16 + c0 + e];
    float cs[2] = {0.f, 0.f};
    const int swidx = (p * 8 + hw * 4 + cp4) * 8 + r8_;
    float* outp = out + ((size_t)(g * 8 + r8_) * TT) * HH + p * 16 + c0;
    float pend0 = 0.f, pend1 = 0.f;
    bool trylocal = valid;
    int lfails = 0;

    for (int t = 0; t < TT; ++t){
      const int buf = t & 1;
      const u32 tg = (u32)(t - 1);
      const size_t boff = (size_t)((t + 3) & 3) * 2048 + wbase;
      u64 wv[32];
      bool got = false;
      if (trylocal){
        const u64* b0 = gbl + boff;
        const u64* b1 = b0 + 512;
        int rounds = 0;
        for (;;){
          LDL32(b0, b1);
          bool ok = true;
#pragma unroll
          for (int j = 0; j < 32; ++j) ok &= ((u32)(wv[j] >> 32) == tg);
          if (__all(ok)){ got = true; break; }
          if (++rounds >= 16) break;
        }
        if (!got && t >= 1 && ++lfails >= 3) trylocal = false;
      }
      if (!got){
        const u64* m0 = gbm + boff;
        for (;;){
#pragma unroll
          for (int j = 0; j < 32; ++j){
            int kk = j >> 2, jj = j & 3;
            wv[j] = __hip_atomic_load(m0 + kk * 128 + jj * 8,
                                      __ATOMIC_RELAXED, __HIP_MEMORY_SCOPE_AGENT);
          }
          bool ok = true;
#pragma unroll
          for (int j = 0; j < 32; ++j) ok &= ((u32)(wv[j] >> 32) == tg);
          if (__all(ok)) break;
        }
      }
      asm volatile("" ::: "memory");
      // deferred out store of step t-1 — lanes<32 ONLY (r16 bug: unguarded race)
      if (t > 0 && lane < 32)
        *(float2*)(outp + (size_t)(t - 1) * HH) = make_float2(pend0, pend1);

      f32x4 acc[4];
#pragma unroll
      for (int n = 0; n < 4; ++n) acc[n] = (f32x4){0.f, 0.f, 0.f, 0.f};
#pragma unroll
      for (int kk = 0; kk < 8; ++kk){
        union { u32 d[4]; bf16x8 v; } af;
#pragma unroll
        for (int jj = 0; jj < 4; ++jj) af.d[jj] = (u32)wv[kk * 4 + jj];
#pragma unroll
        for (int n = 0; n < 4; ++n)
          acc[n] = __builtin_amdgcn_mfma_f32_16x16x32_bf16(af.v, bfrag[n][kk], acc[n], 0, 0, 0);
      }
      for (;;){
        int go = __hip_atomic_load(&sflag[8 + (hw ^ 1)], __ATOMIC_RELAXED, __HIP_MEMORY_SCOPE_WORKGROUP);
        if (go >= t - 2) break;
      }
      float* hp_ = &hpart[buf][hw][0];
#pragma unroll
      for (int G = 0; G < 4; ++G)
#pragma unroll
        for (int reg = 0; reg < 4; ++reg)
          hp_[G * 272 + (khi * 4 + reg) * 17 + llo] = acc[G][reg];
      asm volatile("s_waitcnt lgkmcnt(0)" ::: "memory");
      __hip_atomic_store(&sflag[4 + buf * 2 + hw], t, __ATOMIC_RELAXED, __HIP_MEMORY_SCOPE_WORKGROUP);
      for (;;){
        int f0 = __hip_atomic_load(&sflag[buf * 2],     __ATOMIC_RELAXED, __HIP_MEMORY_SCOPE_WORKGROUP);
        int f1 = __hip_atomic_load(&sflag[buf * 2 + 1], __ATOMIC_RELAXED, __HIP_MEMORY_SCOPE_WORKGROUP);
        int f2 = __hip_atomic_load(&sflag[4 + buf * 2 + (hw ^ 1)], __ATOMIC_RELAXED, __HIP_MEMORY_SCOPE_WORKGROUP);
        if (f0 >= t && f1 >= t && f2 >= t) break;
      }
      asm volatile("s_waitcnt lgkmcnt(0)" ::: "memory");
      __builtin_amdgcn_sched_barrier(0);

      // gate pre-activations, r14's exact order: x0 + x1 + h0 + h1 + bias
      const float* x0 = &xpart[buf][0][0];
      const float* x1 = &xpart[buf][1][0];
      const float* h0p = &hpart[buf][0][0];
      const float* h1p = &hpart[buf][1][0];
      float aG[2][4];
#pragma unroll
      for (int e = 0; e < 2; ++e)
#pragma unroll
        for (int G = 0; G < 4; ++G){
          int idx = G * 272 + r8_ * 17 + c0 + e;
          aG[e][G] = x0[idx] + x1[idx] + h0p[idx] + h1p[idx] + bia[e][G];
        }
      asm volatile("s_waitcnt lgkmcnt(0)" ::: "memory");
      __builtin_amdgcn_sched_barrier(0);
      __hip_atomic_store(&sflag[8 + hw], t, __ATOMIC_RELAXED, __HIP_MEMORY_SCOPE_WORKGROUP);

      if (lane < 32){
        float hv[2]; u32 h16[2];
#pragma unroll
        for (int e = 0; e < 2; ++e){
          float gi = 1.f / (1.f + __expf(-aG[e][0]));
          float gf = 1.f / (1.f + __expf(-aG[e][1]));
          float go = 1.f / (1.f + __expf(-aG[e][2]));
          float e2 = __expf(-2.f * fabsf(aG[e][3]));
          float gg = __builtin_copysignf((1.f - e2) / (1.f + e2), aG[e][3]);
          float c  = gf * cs[e] + gi * gg;
          cs[e] = c;
          float ec = __expf(-2.f * fabsf(c));
          float th = __builtin_copysignf((1.f - ec) / (1.f + ec), c);
          hv[e] = go * th;
          h16[e] = f2bf(hv[e]);
        }
        // dual-publish: local plain store (XCD L2) first, then MALL mirror
        u64 word = ((u64)(u32)t << 32) | ((u64)h16[1] << 16) | (u64)h16[0];
        size_t soff = (size_t)(t & 3) * 2048 + swidx;
        u64* lp = gbl + soff;
        asm volatile("global_store_dwordx2 %0, %1, off" :: "v"(lp), "v"(word) : "memory");
        __hip_atomic_store(gbm + soff, word, __ATOMIC_RELAXED, __HIP_MEMORY_SCOPE_AGENT);
        pend0 = hv[0]; pend1 = hv[1];
      }
    }
    if (lane < 32) *(float2*)(outp + (size_t)(TT - 1) * HH) = make_float2(pend0, pend1);
  }
}

extern "C" void kernel_launch(void* const* d_in, const int* in_sizes, int n_in,
                              void* d_out, int out_size, void* d_ws, size_t ws_size,
                              hipStream_t stream){
  const float* x  = (const float*)d_in[0];
  const float* h0 = (const float*)d_in[1];
  const float* Wx = (const float*)d_in[2];
  const float* Wh = (const float*)d_in[3];
  const float* b  = (const float*)d_in[4];
  float* out = (float*)d_out;

  unsigned char* ws = (unsigned char*)d_ws;
  u16*  wp   = (u16*)(ws + OFF_WPACK);
  unsigned char* xs = ws + OFF_XS;
  u64*  hbl  = (u64*)(ws + OFF_HBL);
  u64*  hbm  = (u64*)(ws + OFF_HBM);
  u32*  org  = (u32*)(ws + OFF_ORG);

  hipLaunchKernelGGL(k_clear,   dim3(256),   dim3(256), 0, stream, hbl, hbm, org);
  hipLaunchKernelGGL(k_pack_w,  dim3(1024),  dim3(256), 0, stream, Wx, Wh, wp);
  hipLaunchKernelGGL(k_conv_x,  dim3(16384), dim3(256), 0, stream, x, xs);
  hipLaunchKernelGGL(k_conv_h0, dim3(64),    dim3(256), 0, stream, h0, hbl, hbm);
  hipLaunchKernelGGL(k_lstm,    dim3(256),   dim3(256), 0, stream, b, out, wp, xs, hbl, hbm, org);
}